// Round 5
// baseline (433.783 us; speedup 1.0000x reference)
//
#include <hip/hip_runtime.h>
#include <stdint.h>

#define BATCH 2
#define NPTS  4096
#define HDIM  256
#define KNN   24
#define NEDGE (BATCH * NPTS * KNN)  // 196608
#define CAP   128
#define TGT   48  // candidate-selection target (>= KNN + margin)

typedef __attribute__((ext_vector_type(8))) short bf16x8;
typedef __attribute__((ext_vector_type(4))) float f32x4;
typedef __attribute__((ext_vector_type(8))) unsigned short u16x8;

__device__ __forceinline__ unsigned short f2bf(float f) {
  union { float f; unsigned int u; } x; x.f = f;
  unsigned int u = x.u;
  unsigned int r = (u + 0x7fffu + ((u >> 16) & 1u)) >> 16;  // RNE
  return (unsigned short)r;
}

__device__ __forceinline__ void gl2lds16(const void* g, void* l) {
  __builtin_amdgcn_global_load_lds(
      (const __attribute__((address_space(1))) unsigned int*)g,
      (__attribute__((address_space(3))) unsigned int*)l, 16, 0, 0);
}

// ---------------- K0: squared norms of h rows + bf16 copy of h ----------------
__global__ __launch_bounds__(256) void k_sqnorm(const float* __restrict__ h,
                                                float* __restrict__ sq,
                                                unsigned short* __restrict__ hb) {
  int t = threadIdx.x, lane = t & 63, w = t >> 6;
  int row = blockIdx.x * 4 + w;  // 0..8191
  const float* hr = h + (size_t)row * HDIM;
  float4 v = *(const float4*)(hr + lane * 4);
  ushort4 o;
  o.x = f2bf(v.x); o.y = f2bf(v.y); o.z = f2bf(v.z); o.w = f2bf(v.w);
  *(ushort4*)(hb + (size_t)row * HDIM + lane * 4) = o;
  float s = v.x * v.x + v.y * v.y + v.z * v.z + v.w * v.w;
#pragma unroll
  for (int off = 32; off; off >>= 1) s += __shfl_down(s, off);
  if (lane == 0) sq[row] = s;
}

// ---------------- K0b: transpose+convert W2/W3 to bf16 (N x K) ----------------
__global__ __launch_bounds__(256) void k_convw(const float* __restrict__ W2,
                                               const float* __restrict__ W3,
                                               unsigned short* __restrict__ w2bt,
                                               unsigned short* __restrict__ w3bt) {
  int t = blockIdx.x * 256 + threadIdx.x;  // 0..65535
  int k = t >> 8, n = t & 255;
  w2bt[n * 256 + k] = f2bf(W2[t]);
  w3bt[n * 256 + k] = f2bf(W3[t]);
}

// ---------------- K1: distance GEMM via bf16 MFMA, emits u16 monotone keys ----------------
// key[b][i][j] = top16(monotone_u32(sq[b*NPTS+j] - 2 * sum_k hb[i][k]*hb[j][k]))
__global__ __launch_bounds__(256) void k_dist(const unsigned short* __restrict__ hb,
                                              const float* __restrict__ sq,
                                              unsigned short* __restrict__ D16) {
  __shared__ unsigned short At[128 * 32];
  __shared__ unsigned short Bl[128 * 32];
  int b = blockIdx.z;
  int i0 = blockIdx.y * 128, j0 = blockIdx.x * 128;
  const unsigned short* A = hb + (size_t)b * NPTS * HDIM;
  int t = threadIdx.x, lane = t & 63, w = t >> 6;
  int wm = w >> 1, wn = w & 1;
  int lr = lane & 15, lk = (lane >> 4) * 8;
  f32x4 acc[4][4];
#pragma unroll
  for (int i = 0; i < 4; ++i)
#pragma unroll
    for (int j = 0; j < 4; ++j) acc[i][j] = (f32x4){0.f, 0.f, 0.f, 0.f};

  for (int k0 = 0; k0 < HDIM; k0 += 32) {
#pragma unroll
    for (int c = 0; c < 2; ++c) {
      int o = c * 256 + t;
      int row = o >> 2, cb = (o & 3) * 16;
      gl2lds16((const char*)A + ((size_t)(i0 + row) * HDIM + k0) * 2 + cb, (char*)At + o * 16);
      gl2lds16((const char*)A + ((size_t)(j0 + row) * HDIM + k0) * 2 + cb, (char*)Bl + o * 16);
    }
    __syncthreads();
    bf16x8 af[4], bfr[4];
#pragma unroll
    for (int i = 0; i < 4; ++i) af[i] = *(const bf16x8*)&At[(wm * 64 + i * 16 + lr) * 32 + lk];
#pragma unroll
    for (int j = 0; j < 4; ++j) bfr[j] = *(const bf16x8*)&Bl[(wn * 64 + j * 16 + lr) * 32 + lk];
#pragma unroll
    for (int i = 0; i < 4; ++i)
#pragma unroll
      for (int j = 0; j < 4; ++j)
        acc[i][j] = __builtin_amdgcn_mfma_f32_16x16x32_bf16(af[i], bfr[j], acc[i][j], 0, 0, 0);
    __syncthreads();
  }
#pragma unroll
  for (int i = 0; i < 4; ++i)
#pragma unroll
    for (int j = 0; j < 4; ++j)
#pragma unroll
      for (int r = 0; r < 4; ++r) {
        int gi = i0 + wm * 64 + i * 16 + (lane >> 4) * 4 + r;
        int gj = j0 + wn * 64 + j * 16 + lr;
        union { float f; unsigned u; } x;
        x.f = sq[b * NPTS + gj] - 2.f * acc[i][j][r];
        unsigned m = x.u ^ ((unsigned)((int)x.u >> 31) | 0x80000000u);
        D16[((size_t)b * NPTS + gi) * NPTS + gj] = (unsigned short)(m >> 16);
      }
}

// ---------------- K2: top-K, wave-per-row, barrier-free radix select + f64 re-rank ----------------
__global__ __launch_bounds__(256) void k_topk(const unsigned short* __restrict__ D16,
                                              const float* __restrict__ h,
                                              int* __restrict__ idxout) {
  int w = threadIdx.x >> 6, lane = threadIdx.x & 63;
  int bn = blockIdx.x * 4 + w;  // row 0..8191
  int b = bn >> 12;
  const u16x8* rowv = (const u16x8*)(D16 + (size_t)bn * NPTS);

  __shared__ unsigned int hist[4][256];
  __shared__ int s_ci[4][CAP];
  __shared__ double s_dv[4][CAP];
  __shared__ unsigned int s_cnt[4];

  unsigned int* H = hist[w];
  if (lane == 0) s_cnt[w] = 0;

  // 64 keys per lane, coalesced 16B loads
  u16x8 kv[8];
#pragma unroll
  for (int c = 0; c < 8; ++c) kv[c] = rowv[c * 64 + lane];

  // ---- pass 1: 256-bin histogram of high byte (per-wave table, in-order LDS) ----
#pragma unroll
  for (int i = 0; i < 4; ++i) H[lane * 4 + i] = 0;
#pragma unroll
  for (int c = 0; c < 8; ++c)
#pragma unroll
    for (int j = 0; j < 8; ++j) atomicAdd(&H[kv[c][j] >> 8], 1u);

  unsigned s = H[lane * 4] + H[lane * 4 + 1] + H[lane * 4 + 2] + H[lane * 4 + 3];
  unsigned ps = s;
#pragma unroll
  for (int off = 1; off < 64; off <<= 1) {
    unsigned o = __shfl_up(ps, off);
    if (lane >= off) ps += o;
  }
  unsigned before = ps - s;
  bool qual = (ps >= TGT) && (before < TGT);
  unsigned long long mask = __ballot(qual);
  int src = __ffsll(mask) - 1;
  unsigned B = 0, cb = 0;
  if (lane == src) {
    unsigned cum = before;
    int bb = lane * 4;
#pragma unroll
    for (int i = 0; i < 4; ++i) {
      unsigned c = H[lane * 4 + i];
      if (cum + c >= TGT) { bb = lane * 4 + i; break; }
      cum += c;
    }
    B = (unsigned)bb; cb = cum;
  }
  B = __shfl(B, src); cb = __shfl(cb, src);

  // ---- pass 2: refine low byte within bin B ----
#pragma unroll
  for (int i = 0; i < 4; ++i) H[lane * 4 + i] = 0;
#pragma unroll
  for (int c = 0; c < 8; ++c)
#pragma unroll
    for (int j = 0; j < 8; ++j) {
      unsigned k = kv[c][j];
      if ((k >> 8) == B) atomicAdd(&H[k & 255u], 1u);
    }
  unsigned s2 = H[lane * 4] + H[lane * 4 + 1] + H[lane * 4 + 2] + H[lane * 4 + 3];
  unsigned ps2 = s2;
#pragma unroll
  for (int off = 1; off < 64; off <<= 1) {
    unsigned o = __shfl_up(ps2, off);
    if (lane >= off) ps2 += o;
  }
  unsigned before2 = ps2 - s2;
  qual = (cb + ps2 >= TGT) && (cb + before2 < TGT);
  mask = __ballot(qual);
  src = __ffsll(mask) - 1;
  unsigned S = 0;
  if (lane == src) {
    unsigned cum = cb + before2;
    int ss = lane * 4;
#pragma unroll
    for (int i = 0; i < 4; ++i) {
      unsigned c = H[lane * 4 + i];
      if (cum + c >= TGT) { ss = lane * 4 + i; break; }
      cum += c;
    }
    S = (unsigned)ss;
  }
  S = __shfl(S, src);
  unsigned ub = (B << 8) + S + 1;  // keys < ub form candidate set, count >= TGT

  // ---- compact candidates ----
#pragma unroll
  for (int c = 0; c < 8; ++c)
#pragma unroll
    for (int j = 0; j < 8; ++j) {
      unsigned k = kv[c][j];
      if (k < ub) {
        unsigned pos = atomicAdd(&s_cnt[w], 1u);
        if (pos < CAP) s_ci[w][pos] = c * 512 + lane * 8 + j;
      }
    }
  int n = (int)s_cnt[w];
  if (n > CAP) n = CAP;

  // ---- exact f64 re-rank ----
  const float* hbase = h + (size_t)b * NPTS * HDIM;
  const float* hn = hbase + (size_t)(bn & 4095) * HDIM;
  float4 a = *(const float4*)(hn + lane * 4);
  for (int c = 0; c < n; ++c) {
    const float* hm = hbase + (size_t)s_ci[w][c] * HDIM;
    float4 bv = *(const float4*)(hm + lane * 4);
    double d0 = (double)a.x - (double)bv.x;
    double d1 = (double)a.y - (double)bv.y;
    double d2 = (double)a.z - (double)bv.z;
    double d3 = (double)a.w - (double)bv.w;
    double d = d0 * d0 + d1 * d1 + d2 * d2 + d3 * d3;
#pragma unroll
    for (int off = 32; off; off >>= 1) d += __shfl_down(d, off);
    if (lane == 0) s_dv[w][c] = d;
  }

  // ---- branch-free rank selection (stable: ties by smaller index) ----
  for (int c = lane; c < n; c += 64) {
    double dc = s_dv[w][c];
    int ic = s_ci[w][c];
    int rank = 0;
    for (int o = 0; o < n; ++o) {
      double dv = s_dv[w][o];
      int io = s_ci[w][o];
      if (dv < dc || (dv == dc && io < ic)) ++rank;
    }
    if (rank < KNN) idxout[(size_t)bn * KNN + rank] = ic;
  }
}

// ---------------- K3: node features C = h @ [W1_hi | W1_hj]  (+b1 on first half) ----------------
__global__ __launch_bounds__(256) void k_nodefeat(const float* __restrict__ h,
                                                  const float* __restrict__ W1,
                                                  const float* __restrict__ b1,
                                                  float* __restrict__ C) {
  int ct = blockIdx.x;            // 0..3 -> output col tile of 128 (of 512)
  int i0 = blockIdx.y * 128;      // rows of h (8192 total)
  int wrow = (ct < 2) ? 3 : 259;  // W1 row base for this half
  int t = threadIdx.x, tx = t & 15, ty = t >> 4;
  __shared__ float TA[128][17];
  __shared__ float TB[16][128];
  float acc[8][8];
#pragma unroll
  for (int i = 0; i < 8; ++i)
#pragma unroll
    for (int j = 0; j < 8; ++j) acc[i][j] = 0.f;
  int srow = t >> 1, sc = (t & 1) * 8;
  int brow = t >> 4, bc = (t & 15) * 8;

  for (int k0 = 0; k0 < HDIM; k0 += 16) {
    const float* pa = &h[(size_t)(i0 + srow) * HDIM + k0 + sc];
    float4 a0 = *(const float4*)pa, a1 = *(const float4*)(pa + 4);
    const float* pb = &W1[(size_t)(wrow + k0 + brow) * HDIM + (ct & 1) * 128 + bc];
    float4 b0 = *(const float4*)pb, b1v = *(const float4*)(pb + 4);
    __syncthreads();
    TA[srow][sc + 0] = a0.x; TA[srow][sc + 1] = a0.y; TA[srow][sc + 2] = a0.z; TA[srow][sc + 3] = a0.w;
    TA[srow][sc + 4] = a1.x; TA[srow][sc + 5] = a1.y; TA[srow][sc + 6] = a1.z; TA[srow][sc + 7] = a1.w;
    *(float4*)&TB[brow][bc] = b0;
    *(float4*)&TB[brow][bc + 4] = b1v;
    __syncthreads();
#pragma unroll
    for (int kk = 0; kk < 16; ++kk) {
      float av[8], bv[8];
#pragma unroll
      for (int i = 0; i < 8; ++i) av[i] = TA[ty + 16 * i][kk];
#pragma unroll
      for (int j = 0; j < 8; ++j) bv[j] = TB[kk][tx + 16 * j];
#pragma unroll
      for (int i = 0; i < 8; ++i)
#pragma unroll
        for (int j = 0; j < 8; ++j) acc[i][j] += av[i] * bv[j];
    }
  }
#pragma unroll
  for (int i = 0; i < 8; ++i) {
    int gi = i0 + ty + 16 * i;
#pragma unroll
    for (int j = 0; j < 8; ++j) {
      int gc = ct * 128 + tx + 16 * j;
      float vv = acc[i][j];
      if (gc < 256) vv += b1[gc];
      C[(size_t)gi * 512 + gc] = vv;
    }
  }
}

// ---------------- K4: assemble x1 = leaky(A[i] + B[j] + p_ij @ W1p) per edge ----------------
__global__ __launch_bounds__(256) void k_edge1(const float* __restrict__ p,
                                               const float* __restrict__ R,
                                               const float* __restrict__ W1,
                                               const float* __restrict__ C,
                                               const int* __restrict__ idx,
                                               unsigned short* __restrict__ x1) {
  int bn = blockIdx.x;
  int b = bn >> 12;
  int t = threadIdx.x;
  __shared__ int   s_j[KNN];
  __shared__ float s_diff[KNN][3];
  __shared__ float s_pij[KNN][3];
  if (t < KNN) s_j[t] = idx[(size_t)bn * KNN + t];
  __syncthreads();
  if (t < KNN * 3) {
    int k = t / 3, d = t % 3;
    int j = s_j[k];
    s_diff[k][d] = p[((size_t)(b << 12) + j) * 3 + d] - p[(size_t)bn * 3 + d];
  }
  __syncthreads();
  if (t < KNN * 3) {
    int k = t / 3, i = t % 3;
    const float* Rp = R + (size_t)bn * 9;
    s_pij[k][i] = Rp[i] * s_diff[k][0] + Rp[3 + i] * s_diff[k][1] + Rp[6 + i] * s_diff[k][2];
  }
  __syncthreads();
  float w0 = W1[t], w1 = W1[256 + t], w2 = W1[512 + t];
  float a = C[(size_t)bn * 512 + t];  // includes b1
  for (int k = 0; k < KNN; ++k) {
    int j = s_j[k];
    float vv = a + C[((size_t)(b << 12) + j) * 512 + 256 + t]
             + s_pij[k][0] * w0 + s_pij[k][1] * w1 + s_pij[k][2] * w2;
    vv = vv >= 0.f ? vv : 0.1f * vv;
    x1[((size_t)bn * KNN + k) * HDIM + t] = f2bf(vv);
  }
}

// ---------------- K5: x2 = leaky(x1 @ W2 + b2), bf16 MFMA 128x128 tile ----------------
__global__ __launch_bounds__(256) void k_gemm2(const unsigned short* __restrict__ A,
                                               const unsigned short* __restrict__ Bt,
                                               const float* __restrict__ bias,
                                               unsigned short* __restrict__ Out) {
  __shared__ unsigned short At[128 * 32];
  __shared__ unsigned short Bl[128 * 32];
  int t = threadIdx.x, lane = t & 63, w = t >> 6;
  int wm = w >> 1, wn = w & 1;
  int m0 = blockIdx.x * 128, n0 = blockIdx.y * 128;
  int lr = lane & 15, lk = (lane >> 4) * 8;
  f32x4 acc[4][4];
#pragma unroll
  for (int i = 0; i < 4; ++i)
#pragma unroll
    for (int j = 0; j < 4; ++j) acc[i][j] = (f32x4){0.f, 0.f, 0.f, 0.f};

  for (int k0 = 0; k0 < 256; k0 += 32) {
#pragma unroll
    for (int c = 0; c < 2; ++c) {
      int o = c * 256 + t;
      int row = o >> 2, cb = (o & 3) * 16;
      gl2lds16((const char*)A + ((size_t)(m0 + row) * 256 + k0) * 2 + cb, (char*)At + o * 16);
      gl2lds16((const char*)Bt + ((size_t)(n0 + row) * 256 + k0) * 2 + cb, (char*)Bl + o * 16);
    }
    __syncthreads();
    bf16x8 af[4], bfr[4];
#pragma unroll
    for (int i = 0; i < 4; ++i) af[i] = *(const bf16x8*)&At[(wm * 64 + i * 16 + lr) * 32 + lk];
#pragma unroll
    for (int j = 0; j < 4; ++j) bfr[j] = *(const bf16x8*)&Bl[(wn * 64 + j * 16 + lr) * 32 + lk];
#pragma unroll
    for (int i = 0; i < 4; ++i)
#pragma unroll
      for (int j = 0; j < 4; ++j)
        acc[i][j] = __builtin_amdgcn_mfma_f32_16x16x32_bf16(af[i], bfr[j], acc[i][j], 0, 0, 0);
    __syncthreads();
  }
#pragma unroll
  for (int i = 0; i < 4; ++i)
#pragma unroll
    for (int j = 0; j < 4; ++j)
#pragma unroll
      for (int r = 0; r < 4; ++r) {
        int grow = m0 + wm * 64 + i * 16 + (lane >> 4) * 4 + r;
        int gcol = n0 + wn * 64 + j * 16 + lr;
        float vv = acc[i][j][r] + bias[gcol];
        vv = vv >= 0.f ? vv : 0.1f * vv;
        Out[(size_t)grow * 256 + gcol] = f2bf(vv);
      }
}

// ---------------- K6: x3 = x2 @ W3 (+b3), fused max over K=24 groups ----------------
__global__ __launch_bounds__(256) void k_gemm3max(const unsigned short* __restrict__ A,
                                                  const unsigned short* __restrict__ Bt,
                                                  const float* __restrict__ b3,
                                                  float* __restrict__ out) {
  __shared__ float Cs[128 * 129];  // 66 KB; staging tiles aliased at the front
  unsigned short* At = (unsigned short*)Cs;
  unsigned short* Bl = At + 128 * 32;
  int t = threadIdx.x, lane = t & 63, w = t >> 6;
  int wm = w >> 1, wn = w & 1;
  int g0 = blockIdx.x * 5;
  int m0 = blockIdx.x * 120;
  int n0 = blockIdx.y * 128;
  int lr = lane & 15, lk = (lane >> 4) * 8;
  f32x4 acc[4][4];
#pragma unroll
  for (int i = 0; i < 4; ++i)
#pragma unroll
    for (int j = 0; j < 4; ++j) acc[i][j] = (f32x4){0.f, 0.f, 0.f, 0.f};

  for (int k0 = 0; k0 < 256; k0 += 32) {
#pragma unroll
    for (int c = 0; c < 2; ++c) {
      int o = c * 256 + t;
      int row = o >> 2, cb = (o & 3) * 16;
      int ar = m0 + row;
      if (ar > NEDGE - 1) ar = NEDGE - 1;
      gl2lds16((const char*)A + ((size_t)ar * 256 + k0) * 2 + cb, (char*)At + o * 16);
      gl2lds16((const char*)Bt + ((size_t)(n0 + row) * 256 + k0) * 2 + cb, (char*)Bl + o * 16);
    }
    __syncthreads();
    bf16x8 af[4], bfr[4];
#pragma unroll
    for (int i = 0; i < 4; ++i) af[i] = *(const bf16x8*)&At[(wm * 64 + i * 16 + lr) * 32 + lk];
#pragma unroll
    for (int j = 0; j < 4; ++j) bfr[j] = *(const bf16x8*)&Bl[(wn * 64 + j * 16 + lr) * 32 + lk];
#pragma unroll
    for (int i = 0; i < 4; ++i)
#pragma unroll
      for (int j = 0; j < 4; ++j)
        acc[i][j] = __builtin_amdgcn_mfma_f32_16x16x32_bf16(af[i], bfr[j], acc[i][j], 0, 0, 0);
    __syncthreads();
  }
#pragma unroll
  for (int i = 0; i < 4; ++i)
#pragma unroll
    for (int j = 0; j < 4; ++j)
#pragma unroll
      for (int r = 0; r < 4; ++r)
        Cs[(wm * 64 + i * 16 + (lane >> 4) * 4 + r) * 129 + wn * 64 + j * 16 + lr] = acc[i][j][r];
  __syncthreads();
  for (int o = t; o < 5 * 128; o += 256) {
    int g = o >> 7, col = o & 127;
    int gg = g0 + g;
    if (gg < BATCH * NPTS) {
      float mx = -3.0e38f;
#pragma unroll
      for (int r = 0; r < KNN; ++r) mx = fmaxf(mx, Cs[(g * 24 + r) * 129 + col]);
      int gcol = n0 + col;
      out[(size_t)gg * 256 + gcol] = mx + b3[gcol];
    }
  }
}

extern "C" void kernel_launch(void* const* d_in, const int* in_sizes, int n_in,
                              void* d_out, int out_size, void* d_ws, size_t ws_size,
                              hipStream_t stream) {
  const float* p  = (const float*)d_in[0];
  const float* R  = (const float*)d_in[1];
  const float* h  = (const float*)d_in[2];
  const float* W1 = (const float*)d_in[3];
  const float* b1 = (const float*)d_in[4];
  const float* W2 = (const float*)d_in[5];
  const float* b2 = (const float*)d_in[6];
  const float* W3 = (const float*)d_in[7];
  const float* b3 = (const float*)d_in[8];
  float* out = (float*)d_out;
  char* ws = (char*)d_ws;

  float*          sq   = (float*)(ws + 0);                   //   32768
  int*            idx  = (int*)(ws + 32768);                 //  786432
  float*          C    = (float*)(ws + 819200);              // 16777216
  unsigned short* w2bt = (unsigned short*)(ws + 17596416);   //  131072
  unsigned short* w3bt = (unsigned short*)(ws + 17727488);   //  131072
  char* big = ws + 17858560;
  unsigned short* x1  = (unsigned short*)big;                // 100663296
  unsigned short* x2  = (unsigned short*)(big + 100663296);  // 100663296
  unsigned short* D16 = (unsigned short*)big;                // 67108864, dead before x1 written
  // hb: bf16 copy of h; past D16's end, inside x2's region (disjoint lifetimes)
  unsigned short* hbb = (unsigned short*)(big + 134217728);  // 4194304

  k_sqnorm  <<<dim3(2048),     dim3(256), 0, stream>>>(h, sq, hbb);
  k_convw   <<<dim3(256),      dim3(256), 0, stream>>>(W2, W3, w2bt, w3bt);
  k_dist    <<<dim3(32, 32, 2),dim3(256), 0, stream>>>(hbb, sq, D16);
  k_topk    <<<dim3(2048),     dim3(256), 0, stream>>>(D16, h, idx);
  k_nodefeat<<<dim3(4, 64),    dim3(256), 0, stream>>>(h, W1, b1, C);
  k_edge1   <<<dim3(8192),     dim3(256), 0, stream>>>(p, R, W1, C, idx, x1);
  k_gemm2   <<<dim3(1536, 2),  dim3(256), 0, stream>>>(x1, w2bt, b2, x2);
  k_gemm3max<<<dim3(1639, 2),  dim3(256), 0, stream>>>(x2, w3bt, b3, out);
}

// Round 6
// 333.935 us; speedup vs baseline: 1.2990x; 1.2990x over previous
//
#include <hip/hip_runtime.h>
#include <stdint.h>

#define BATCH 2
#define NPTS  4096
#define HDIM  256
#define KNN   24
#define NEDGE (BATCH * NPTS * KNN)  // 196608
#define CAP   128
#define TGT   48  // candidate-selection target (>= KNN + margin)

typedef __attribute__((ext_vector_type(8))) short bf16x8;
typedef __attribute__((ext_vector_type(4))) float f32x4;
typedef __attribute__((ext_vector_type(8))) unsigned short u16x8;

__device__ __forceinline__ unsigned short f2bf(float f) {
  union { float f; unsigned int u; } x; x.f = f;
  unsigned int u = x.u;
  unsigned int r = (u + 0x7fffu + ((u >> 16) & 1u)) >> 16;  // RNE
  return (unsigned short)r;
}

__device__ __forceinline__ void gl2lds16(const void* g, void* l) {
  __builtin_amdgcn_global_load_lds(
      (const __attribute__((address_space(1))) unsigned int*)g,
      (__attribute__((address_space(3))) unsigned int*)l, 16, 0, 0);
}

// ---------------- K0: squared norms of h rows + bf16 copy of h ----------------
__global__ __launch_bounds__(256) void k_sqnorm(const float* __restrict__ h,
                                                float* __restrict__ sq,
                                                unsigned short* __restrict__ hb) {
  int t = threadIdx.x, lane = t & 63, w = t >> 6;
  int row = blockIdx.x * 4 + w;  // 0..8191
  const float* hr = h + (size_t)row * HDIM;
  float4 v = *(const float4*)(hr + lane * 4);
  ushort4 o;
  o.x = f2bf(v.x); o.y = f2bf(v.y); o.z = f2bf(v.z); o.w = f2bf(v.w);
  *(ushort4*)(hb + (size_t)row * HDIM + lane * 4) = o;
  float s = v.x * v.x + v.y * v.y + v.z * v.z + v.w * v.w;
#pragma unroll
  for (int off = 32; off; off >>= 1) s += __shfl_down(s, off);
  if (lane == 0) sq[row] = s;
}

// ---------------- K0b: transpose+convert W2/W3 to bf16 (N x K) ----------------
__global__ __launch_bounds__(256) void k_convw(const float* __restrict__ W2,
                                               const float* __restrict__ W3,
                                               unsigned short* __restrict__ w2bt,
                                               unsigned short* __restrict__ w3bt) {
  int t = blockIdx.x * 256 + threadIdx.x;  // 0..65535
  int k = t >> 8, n = t & 255;
  w2bt[n * 256 + k] = f2bf(W2[t]);
  w3bt[n * 256 + k] = f2bf(W3[t]);
}

// ---------------- K1: distance GEMM via bf16 MFMA, emits u16 monotone keys ----------------
// key[b][i][j] = top16(monotone_u32(sq[b*NPTS+j] - 2 * sum_k hb[i][k]*hb[j][k]))
__global__ __launch_bounds__(256) void k_dist(const unsigned short* __restrict__ hb,
                                              const float* __restrict__ sq,
                                              unsigned short* __restrict__ D16) {
  __shared__ unsigned short At[128 * 32];
  __shared__ unsigned short Bl[128 * 32];
  int b = blockIdx.z;
  int i0 = blockIdx.y * 128, j0 = blockIdx.x * 128;
  const unsigned short* A = hb + (size_t)b * NPTS * HDIM;
  int t = threadIdx.x, lane = t & 63, w = t >> 6;
  int wm = w >> 1, wn = w & 1;
  int lr = lane & 15, lk = (lane >> 4) * 8;
  f32x4 acc[4][4];
#pragma unroll
  for (int i = 0; i < 4; ++i)
#pragma unroll
    for (int j = 0; j < 4; ++j) acc[i][j] = (f32x4){0.f, 0.f, 0.f, 0.f};

  for (int k0 = 0; k0 < HDIM; k0 += 32) {
#pragma unroll
    for (int c = 0; c < 2; ++c) {
      int o = c * 256 + t;
      int row = o >> 2, cb = (o & 3) * 16;
      gl2lds16((const char*)A + ((size_t)(i0 + row) * HDIM + k0) * 2 + cb, (char*)At + o * 16);
      gl2lds16((const char*)A + ((size_t)(j0 + row) * HDIM + k0) * 2 + cb, (char*)Bl + o * 16);
    }
    __syncthreads();
    bf16x8 af[4], bfr[4];
#pragma unroll
    for (int i = 0; i < 4; ++i) af[i] = *(const bf16x8*)&At[(wm * 64 + i * 16 + lr) * 32 + lk];
#pragma unroll
    for (int j = 0; j < 4; ++j) bfr[j] = *(const bf16x8*)&Bl[(wn * 64 + j * 16 + lr) * 32 + lk];
#pragma unroll
    for (int i = 0; i < 4; ++i)
#pragma unroll
      for (int j = 0; j < 4; ++j)
        acc[i][j] = __builtin_amdgcn_mfma_f32_16x16x32_bf16(af[i], bfr[j], acc[i][j], 0, 0, 0);
    __syncthreads();
  }
#pragma unroll
  for (int i = 0; i < 4; ++i)
#pragma unroll
    for (int j = 0; j < 4; ++j)
#pragma unroll
      for (int r = 0; r < 4; ++r) {
        int gi = i0 + wm * 64 + i * 16 + (lane >> 4) * 4 + r;
        int gj = j0 + wn * 64 + j * 16 + lr;
        union { float f; unsigned u; } x;
        x.f = sq[b * NPTS + gj] - 2.f * acc[i][j][r];
        unsigned m = x.u ^ ((unsigned)((int)x.u >> 31) | 0x80000000u);
        D16[((size_t)b * NPTS + gi) * NPTS + gj] = (unsigned short)(m >> 16);
      }
}

// ---------------- K2: top-K, wave-per-row, register binary-search select + f64 re-rank ----------------
__global__ __launch_bounds__(256) void k_topk(const unsigned short* __restrict__ D16,
                                              const float* __restrict__ h,
                                              int* __restrict__ idxout) {
  int w = threadIdx.x >> 6, lane = threadIdx.x & 63;
  int bn = blockIdx.x * 4 + w;  // row 0..8191
  int b = bn >> 12;
  const u16x8* rowv = (const u16x8*)(D16 + (size_t)bn * NPTS);

  __shared__ int s_ci[4][CAP];
  __shared__ double s_dv[4][CAP];
  __shared__ unsigned int s_cnt[4];

  if (lane == 0) s_cnt[w] = 0;

  // 64 keys per lane, coalesced 16B loads; unpack to u32 regs (static indexing)
  unsigned k[64];
#pragma unroll
  for (int c = 0; c < 8; ++c) {
    u16x8 v = rowv[c * 64 + lane];
#pragma unroll
    for (int j = 0; j < 8; ++j) k[c * 8 + j] = v[j];
  }

  // wave-uniform bisection: minimal ub in [0,65536] with #{keys < ub} >= TGT.
  // No LDS, no atomics, no divergence: per-lane register compares + shfl_xor sum.
  unsigned lo = 0, hi = 65536;
#pragma unroll 1
  for (int it = 0; it < 16; ++it) {
    unsigned mid = (lo + hi) >> 1;
    unsigned cnt = 0;
#pragma unroll
    for (int i = 0; i < 64; ++i) cnt += (k[i] < mid) ? 1u : 0u;
#pragma unroll
    for (int off = 1; off < 64; off <<= 1) cnt += __shfl_xor(cnt, off);
    if (cnt >= TGT) hi = mid; else lo = mid;
  }
  unsigned ub = hi;  // count(<ub) >= TGT, count(<ub-1) < TGT -> n ~= TGT + ties

  // ---- compact candidates (tiny atomic traffic: ~TGT per wave) ----
#pragma unroll
  for (int i = 0; i < 64; ++i) {
    if (k[i] < ub) {
      unsigned pos = atomicAdd(&s_cnt[w], 1u);
      if (pos < CAP) s_ci[w][pos] = (i >> 3) * 512 + lane * 8 + (i & 7);
    }
  }
  int n = (int)s_cnt[w];
  if (n > CAP) n = CAP;

  // ---- exact f64 re-rank ----
  const float* hbase = h + (size_t)b * NPTS * HDIM;
  const float* hn = hbase + (size_t)(bn & 4095) * HDIM;
  float4 a = *(const float4*)(hn + lane * 4);
  for (int c = 0; c < n; ++c) {
    const float* hm = hbase + (size_t)s_ci[w][c] * HDIM;
    float4 bv = *(const float4*)(hm + lane * 4);
    double d0 = (double)a.x - (double)bv.x;
    double d1 = (double)a.y - (double)bv.y;
    double d2 = (double)a.z - (double)bv.z;
    double d3 = (double)a.w - (double)bv.w;
    double d = d0 * d0 + d1 * d1 + d2 * d2 + d3 * d3;
#pragma unroll
    for (int off = 32; off; off >>= 1) d += __shfl_down(d, off);
    if (lane == 0) s_dv[w][c] = d;
  }

  // ---- branch-free rank selection (stable: ties by smaller index) ----
  for (int c = lane; c < n; c += 64) {
    double dc = s_dv[w][c];
    int ic = s_ci[w][c];
    int rank = 0;
    for (int o = 0; o < n; ++o) {
      double dv = s_dv[w][o];
      int io = s_ci[w][o];
      if (dv < dc || (dv == dc && io < ic)) ++rank;
    }
    if (rank < KNN) idxout[(size_t)bn * KNN + rank] = ic;
  }
}

// ---------------- K3: node features C = h @ [W1_hi | W1_hj]  (+b1 on first half) ----------------
__global__ __launch_bounds__(256) void k_nodefeat(const float* __restrict__ h,
                                                  const float* __restrict__ W1,
                                                  const float* __restrict__ b1,
                                                  float* __restrict__ C) {
  int ct = blockIdx.x;            // 0..3 -> output col tile of 128 (of 512)
  int i0 = blockIdx.y * 128;      // rows of h (8192 total)
  int wrow = (ct < 2) ? 3 : 259;  // W1 row base for this half
  int t = threadIdx.x, tx = t & 15, ty = t >> 4;
  __shared__ float TA[128][17];
  __shared__ float TB[16][128];
  float acc[8][8];
#pragma unroll
  for (int i = 0; i < 8; ++i)
#pragma unroll
    for (int j = 0; j < 8; ++j) acc[i][j] = 0.f;
  int srow = t >> 1, sc = (t & 1) * 8;
  int brow = t >> 4, bc = (t & 15) * 8;

  for (int k0 = 0; k0 < HDIM; k0 += 16) {
    const float* pa = &h[(size_t)(i0 + srow) * HDIM + k0 + sc];
    float4 a0 = *(const float4*)pa, a1 = *(const float4*)(pa + 4);
    const float* pb = &W1[(size_t)(wrow + k0 + brow) * HDIM + (ct & 1) * 128 + bc];
    float4 b0 = *(const float4*)pb, b1v = *(const float4*)(pb + 4);
    __syncthreads();
    TA[srow][sc + 0] = a0.x; TA[srow][sc + 1] = a0.y; TA[srow][sc + 2] = a0.z; TA[srow][sc + 3] = a0.w;
    TA[srow][sc + 4] = a1.x; TA[srow][sc + 5] = a1.y; TA[srow][sc + 6] = a1.z; TA[srow][sc + 7] = a1.w;
    *(float4*)&TB[brow][bc] = b0;
    *(float4*)&TB[brow][bc + 4] = b1v;
    __syncthreads();
#pragma unroll
    for (int kk = 0; kk < 16; ++kk) {
      float av[8], bv[8];
#pragma unroll
      for (int i = 0; i < 8; ++i) av[i] = TA[ty + 16 * i][kk];
#pragma unroll
      for (int j = 0; j < 8; ++j) bv[j] = TB[kk][tx + 16 * j];
#pragma unroll
      for (int i = 0; i < 8; ++i)
#pragma unroll
        for (int j = 0; j < 8; ++j) acc[i][j] += av[i] * bv[j];
    }
  }
#pragma unroll
  for (int i = 0; i < 8; ++i) {
    int gi = i0 + ty + 16 * i;
#pragma unroll
    for (int j = 0; j < 8; ++j) {
      int gc = ct * 128 + tx + 16 * j;
      float vv = acc[i][j];
      if (gc < 256) vv += b1[gc];
      C[(size_t)gi * 512 + gc] = vv;
    }
  }
}

// ---------------- K4: assemble x1 = leaky(A[i] + B[j] + p_ij @ W1p) per edge ----------------
__global__ __launch_bounds__(256) void k_edge1(const float* __restrict__ p,
                                               const float* __restrict__ R,
                                               const float* __restrict__ W1,
                                               const float* __restrict__ C,
                                               const int* __restrict__ idx,
                                               unsigned short* __restrict__ x1) {
  int bn = blockIdx.x;
  int b = bn >> 12;
  int t = threadIdx.x;
  __shared__ int   s_j[KNN];
  __shared__ float s_diff[KNN][3];
  __shared__ float s_pij[KNN][3];
  if (t < KNN) s_j[t] = idx[(size_t)bn * KNN + t];
  __syncthreads();
  if (t < KNN * 3) {
    int k = t / 3, d = t % 3;
    int j = s_j[k];
    s_diff[k][d] = p[((size_t)(b << 12) + j) * 3 + d] - p[(size_t)bn * 3 + d];
  }
  __syncthreads();
  if (t < KNN * 3) {
    int k = t / 3, i = t % 3;
    const float* Rp = R + (size_t)bn * 9;
    s_pij[k][i] = Rp[i] * s_diff[k][0] + Rp[3 + i] * s_diff[k][1] + Rp[6 + i] * s_diff[k][2];
  }
  __syncthreads();
  float w0 = W1[t], w1 = W1[256 + t], w2 = W1[512 + t];
  float a = C[(size_t)bn * 512 + t];  // includes b1
  for (int k = 0; k < KNN; ++k) {
    int j = s_j[k];
    float vv = a + C[((size_t)(b << 12) + j) * 512 + 256 + t]
             + s_pij[k][0] * w0 + s_pij[k][1] * w1 + s_pij[k][2] * w2;
    vv = vv >= 0.f ? vv : 0.1f * vv;
    x1[((size_t)bn * KNN + k) * HDIM + t] = f2bf(vv);
  }
}

// ---------------- K5: x2 = leaky(x1 @ W2 + b2), bf16 MFMA 128x128 tile ----------------
__global__ __launch_bounds__(256) void k_gemm2(const unsigned short* __restrict__ A,
                                               const unsigned short* __restrict__ Bt,
                                               const float* __restrict__ bias,
                                               unsigned short* __restrict__ Out) {
  __shared__ unsigned short At[128 * 32];
  __shared__ unsigned short Bl[128 * 32];
  int t = threadIdx.x, lane = t & 63, w = t >> 6;
  int wm = w >> 1, wn = w & 1;
  int m0 = blockIdx.x * 128, n0 = blockIdx.y * 128;
  int lr = lane & 15, lk = (lane >> 4) * 8;
  f32x4 acc[4][4];
#pragma unroll
  for (int i = 0; i < 4; ++i)
#pragma unroll
    for (int j = 0; j < 4; ++j) acc[i][j] = (f32x4){0.f, 0.f, 0.f, 0.f};

  for (int k0 = 0; k0 < 256; k0 += 32) {
#pragma unroll
    for (int c = 0; c < 2; ++c) {
      int o = c * 256 + t;
      int row = o >> 2, cb = (o & 3) * 16;
      gl2lds16((const char*)A + ((size_t)(m0 + row) * 256 + k0) * 2 + cb, (char*)At + o * 16);
      gl2lds16((const char*)Bt + ((size_t)(n0 + row) * 256 + k0) * 2 + cb, (char*)Bl + o * 16);
    }
    __syncthreads();
    bf16x8 af[4], bfr[4];
#pragma unroll
    for (int i = 0; i < 4; ++i) af[i] = *(const bf16x8*)&At[(wm * 64 + i * 16 + lr) * 32 + lk];
#pragma unroll
    for (int j = 0; j < 4; ++j) bfr[j] = *(const bf16x8*)&Bl[(wn * 64 + j * 16 + lr) * 32 + lk];
#pragma unroll
    for (int i = 0; i < 4; ++i)
#pragma unroll
      for (int j = 0; j < 4; ++j)
        acc[i][j] = __builtin_amdgcn_mfma_f32_16x16x32_bf16(af[i], bfr[j], acc[i][j], 0, 0, 0);
    __syncthreads();
  }
#pragma unroll
  for (int i = 0; i < 4; ++i)
#pragma unroll
    for (int j = 0; j < 4; ++j)
#pragma unroll
      for (int r = 0; r < 4; ++r) {
        int grow = m0 + wm * 64 + i * 16 + (lane >> 4) * 4 + r;
        int gcol = n0 + wn * 64 + j * 16 + lr;
        float vv = acc[i][j][r] + bias[gcol];
        vv = vv >= 0.f ? vv : 0.1f * vv;
        Out[(size_t)grow * 256 + gcol] = f2bf(vv);
      }
}

// ---------------- K6: x3 = x2 @ W3 (+b3), fused max over K=24 groups ----------------
__global__ __launch_bounds__(256) void k_gemm3max(const unsigned short* __restrict__ A,
                                                  const unsigned short* __restrict__ Bt,
                                                  const float* __restrict__ b3,
                                                  float* __restrict__ out) {
  __shared__ float Cs[128 * 129];  // 66 KB; staging tiles aliased at the front
  unsigned short* At = (unsigned short*)Cs;
  unsigned short* Bl = At + 128 * 32;
  int t = threadIdx.x, lane = t & 63, w = t >> 6;
  int wm = w >> 1, wn = w & 1;
  int g0 = blockIdx.x * 5;
  int m0 = blockIdx.x * 120;
  int n0 = blockIdx.y * 128;
  int lr = lane & 15, lk = (lane >> 4) * 8;
  f32x4 acc[4][4];
#pragma unroll
  for (int i = 0; i < 4; ++i)
#pragma unroll
    for (int j = 0; j < 4; ++j) acc[i][j] = (f32x4){0.f, 0.f, 0.f, 0.f};

  for (int k0 = 0; k0 < 256; k0 += 32) {
#pragma unroll
    for (int c = 0; c < 2; ++c) {
      int o = c * 256 + t;
      int row = o >> 2, cb = (o & 3) * 16;
      int ar = m0 + row;
      if (ar > NEDGE - 1) ar = NEDGE - 1;
      gl2lds16((const char*)A + ((size_t)ar * 256 + k0) * 2 + cb, (char*)At + o * 16);
      gl2lds16((const char*)Bt + ((size_t)(n0 + row) * 256 + k0) * 2 + cb, (char*)Bl + o * 16);
    }
    __syncthreads();
    bf16x8 af[4], bfr[4];
#pragma unroll
    for (int i = 0; i < 4; ++i) af[i] = *(const bf16x8*)&At[(wm * 64 + i * 16 + lr) * 32 + lk];
#pragma unroll
    for (int j = 0; j < 4; ++j) bfr[j] = *(const bf16x8*)&Bl[(wn * 64 + j * 16 + lr) * 32 + lk];
#pragma unroll
    for (int i = 0; i < 4; ++i)
#pragma unroll
      for (int j = 0; j < 4; ++j)
        acc[i][j] = __builtin_amdgcn_mfma_f32_16x16x32_bf16(af[i], bfr[j], acc[i][j], 0, 0, 0);
    __syncthreads();
  }
#pragma unroll
  for (int i = 0; i < 4; ++i)
#pragma unroll
    for (int j = 0; j < 4; ++j)
#pragma unroll
      for (int r = 0; r < 4; ++r)
        Cs[(wm * 64 + i * 16 + (lane >> 4) * 4 + r) * 129 + wn * 64 + j * 16 + lr] = acc[i][j][r];
  __syncthreads();
  for (int o = t; o < 5 * 128; o += 256) {
    int g = o >> 7, col = o & 127;
    int gg = g0 + g;
    if (gg < BATCH * NPTS) {
      float mx = -3.0e38f;
#pragma unroll
      for (int r = 0; r < KNN; ++r) mx = fmaxf(mx, Cs[(g * 24 + r) * 129 + col]);
      int gcol = n0 + col;
      out[(size_t)gg * 256 + gcol] = mx + b3[gcol];
    }
  }
}

extern "C" void kernel_launch(void* const* d_in, const int* in_sizes, int n_in,
                              void* d_out, int out_size, void* d_ws, size_t ws_size,
                              hipStream_t stream) {
  const float* p  = (const float*)d_in[0];
  const float* R  = (const float*)d_in[1];
  const float* h  = (const float*)d_in[2];
  const float* W1 = (const float*)d_in[3];
  const float* b1 = (const float*)d_in[4];
  const float* W2 = (const float*)d_in[5];
  const float* b2 = (const float*)d_in[6];
  const float* W3 = (const float*)d_in[7];
  const float* b3 = (const float*)d_in[8];
  float* out = (float*)d_out;
  char* ws = (char*)d_ws;

  float*          sq   = (float*)(ws + 0);                   //   32768
  int*            idx  = (int*)(ws + 32768);                 //  786432
  float*          C    = (float*)(ws + 819200);              // 16777216
  unsigned short* w2bt = (unsigned short*)(ws + 17596416);   //  131072
  unsigned short* w3bt = (unsigned short*)(ws + 17727488);   //  131072
  char* big = ws + 17858560;
  unsigned short* x1  = (unsigned short*)big;                // 100663296
  unsigned short* x2  = (unsigned short*)(big + 100663296);  // 100663296
  unsigned short* D16 = (unsigned short*)big;                // 67108864, dead before x1 written
  // hb: bf16 copy of h; past D16's end, inside x2's region (disjoint lifetimes)
  unsigned short* hbb = (unsigned short*)(big + 134217728);  // 4194304

  k_sqnorm  <<<dim3(2048),     dim3(256), 0, stream>>>(h, sq, hbb);
  k_convw   <<<dim3(256),      dim3(256), 0, stream>>>(W2, W3, w2bt, w3bt);
  k_dist    <<<dim3(32, 32, 2),dim3(256), 0, stream>>>(hbb, sq, D16);
  k_topk    <<<dim3(2048),     dim3(256), 0, stream>>>(D16, h, idx);
  k_nodefeat<<<dim3(4, 64),    dim3(256), 0, stream>>>(h, W1, b1, C);
  k_edge1   <<<dim3(8192),     dim3(256), 0, stream>>>(p, R, W1, C, idx, x1);
  k_gemm2   <<<dim3(1536, 2),  dim3(256), 0, stream>>>(x1, w2bt, b2, x2);
  k_gemm3max<<<dim3(1639, 2),  dim3(256), 0, stream>>>(x2, w3bt, b3, out);
}